// Round 1
// baseline (2405.820 us; speedup 1.0000x reference)
//
#include <hip/hip_runtime.h>
#include <hip/hip_bf16.h>

#define NN 1024
#define BT 32
#define TT 32
#define NTILES ((TT * (TT + 1)) / 2)   // 528

// ---------------------------------------------------------------------------
// Cross-XCD communication WITHOUT cache-wide fences.
// All R/C traffic in the tile kernel uses agent-scope relaxed atomics, which
// compile to sc0/sc1 (L1/L2-bypassing, write-through-to-MALL) vector memory
// ops. Data is therefore at the coherence point when vmcnt retires, so:
//   setflag  = s_waitcnt vmcnt(0)  +  relaxed agent store   (no buffer_wbl2)
//   waitflag = relaxed agent poll  +  compiler barrier      (no buffer_inv)
// This removes ~11.5K full-L2 invalidates / 528 full-L2 writebacks that were
// previously on the tile-DAG critical path.
// ---------------------------------------------------------------------------
__device__ __forceinline__ double gload(const double* p) {
    return __hip_atomic_load(p, __ATOMIC_RELAXED, __HIP_MEMORY_SCOPE_AGENT);
}
__device__ __forceinline__ void gstore(double* p, double v) {
    __hip_atomic_store(p, v, __ATOMIC_RELAXED, __HIP_MEMORY_SCOPE_AGENT);
}

__device__ __forceinline__ void waitflag(const int* f, int a, int b) {
    const int* p = &f[(a * TT + b) << 4];
    while (!__hip_atomic_load(p, __ATOMIC_RELAXED, __HIP_MEMORY_SCOPE_AGENT))
        __builtin_amdgcn_s_sleep(1);
    asm volatile("" ::: "memory");   // compiler-only: keep data loads after poll
}
__device__ __forceinline__ void setflag(int* f, int a, int b) {
    asm volatile("s_waitcnt vmcnt(0)" ::: "memory");  // data at coherence point
    __hip_atomic_store(&f[(a * TT + b) << 4], 1, __ATOMIC_RELAXED, __HIP_MEMORY_SCOPE_AGENT);
}

// ---------------------------------------------------------------------------
__global__ void primes_kernel(const float* __restrict__ feat, int* __restrict__ primes) {
    int i = blockIdx.x * blockDim.x + threadIdx.x;
    if (i < NN) {
        float best = feat[i * NN];
        int arg = 0;
        for (int ch = 1; ch < 4; ++ch) {
            float v = feat[ch * NN * NN + i * NN];
            if (v > best) { best = v; arg = ch; }
        }
        const int P[4] = {2, 3, 5, 7};
        primes[i] = P[arg];
    }
}

__global__ void prep_kernel(const float* __restrict__ con, const int* __restrict__ primes,
                            float* __restrict__ S, double* __restrict__ R,
                            double* __restrict__ C, float* __restrict__ out,
                            int* __restrict__ flags) {
    int idx = blockIdx.x * blockDim.x + threadIdx.x;
    int i = idx >> 10;
    int j = idx & (NN - 1);
    float c = (con[idx] + con[j * NN + i]) * 0.5f;
    int prod = primes[i] * primes[j];
    bool canon = (prod == 14) | (prod == 15) | (prod == 35);
    int d = i - j; if (d < 0) d = -d;
    S[idx] = (canon && d >= 4) ? c : 0.0f;
    R[idx] = 0.0;
    C[idx] = 0.0;
    out[idx] = 0.0f;
    if (idx < TT * TT * 16) flags[idx] = 0;
}

// ---------------------------------------------------------------------------
// Dataflow DP, one wave per 32x32 tile. Exactness: every candidate is one
// fp64 add of stored values; extra candidates are dominated (-1e30+x<0<=dp,
// stale-0 + 0 = 0 <= dp). fmax order-insensitive => DP bitwise == numpy.
// Vtc/DJJc stride 33 doubles -> 2-way LDS banking (free). Vtc[c][32] holds
// the edge row V(aI+32, aJ+c) so the left-split loop covers k=aI+31.
// ---------------------------------------------------------------------------
__global__ __launch_bounds__(64) void nuss_tiles_kernel(double* __restrict__ R,
                                                        double* __restrict__ C,
                                                        const float* __restrict__ S,
                                                        int* __restrict__ flags) {
    __shared__ double DJJc[32][33];                         // DJJc[c][m]=V(aJ+m,aJ+c); [32]=0
    __shared__ double Vtc[32][33];                          // Vtc[c][r]=V(aI+r,aJ+c); [32]=edge
    __shared__ __attribute__((aligned(16))) double Ast[32][34]; // Ast[kk][r]=V(aI+r,kt0+kk)
    __shared__ __attribute__((aligned(16))) double Bst[32][34]; // Bst[kk][c]=V(kt0+kk+1,aJ+c)
    __shared__ double Pld[32][33];
    __shared__ float  Sld[32][32];
    __shared__ double edgeCol[33];                          // V(aI+rr, aJ-1)

    int b = blockIdx.x, dd = 0;
    while (b >= TT - dd) { b -= TT - dd; ++dd; }
    const int I = b, J = b + dd;
    const int aI = I * BT, aJ = J * BT;
    const int lane = threadIdx.x;
    const int r = lane >> 1;
    const int h = lane & 1;

    if (dd == 0) {
        // ---------------- diagonal tile ----------------
        for (int w = 0; w < 16; ++w) {
            int idx = w * 64 + lane; int rr = idx >> 5, cc = idx & 31;
            Sld[rr][cc] = S[(aI + rr) * NN + aI + cc];
        }
        for (int idx = lane; idx < 32 * 33; idx += 64)
            ((double*)Vtc)[idx] = 0.0;
        double vrow[16];
        #pragma unroll
        for (int u = 0; u < 16; ++u) vrow[u] = 0.0;

        for (int s = 1; s <= 31; ++s) {
            int c = r + s;
            bool act = (c <= 31);
            double acc = 0.0;
            if (act) {
                double t0 = 0.0, t1 = 0.0, t2 = 0.0, t3 = 0.0;
                #pragma unroll
                for (int u = 0; u < 16; u += 4) {
                    int k0 = h * 16 + u;
                    t0 = fmax(t0, vrow[u]     + Vtc[c][k0 + 1]);
                    t1 = fmax(t1, vrow[u + 1] + Vtc[c][k0 + 2]);
                    t2 = fmax(t2, vrow[u + 2] + Vtc[c][k0 + 3]);
                    t3 = fmax(t3, vrow[u + 3] + Vtc[c][k0 + 4]);
                }
                acc = fmax(fmax(t0, t1), fmax(t2, t3));
            }
            acc = fmax(acc, __shfl_xor(acc, 1));
            if (act) {
                double best = fmax(acc, Vtc[c - 1][r + 1] + (double)Sld[r][c]);
                if (h == 0) Vtc[c][r] = best;
                #pragma unroll
                for (int u = 0; u < 16; ++u)
                    if (h * 16 + u == c) vrow[u] = best;
            }
        }
        for (int w = 0; w < 16; ++w) {
            int idx = w * 64 + lane; int rr = idx >> 5, cc = idx & 31;
            gstore(&R[(aI + rr) * NN + aI + cc], Vtc[cc][rr]);
        }
        for (int w = 0; w < 16; ++w) {
            int idx = w * 64 + lane; int cc = idx >> 5, rr = idx & 31;
            gstore(&C[(aI + cc) * NN + aI + rr], Vtc[cc][rr]);
        }
        if (lane == 0) setflag(flags, I, I);
        return;
    }

    // ---------------- off-diagonal tile ----------------
    waitflag(flags, I, I);
    waitflag(flags, J, J);

    for (int w = 0; w < 16; ++w) {
        int idx = w * 64 + lane; int cc = idx >> 5, mm = idx & 31;
        DJJc[cc][mm] = gload(&C[(aJ + cc) * NN + aJ + mm]);
    }
    if (lane < 32) DJJc[lane][32] = 0.0;
    for (int w = 0; w < 16; ++w) {
        int idx = w * 64 + lane; int rr = idx >> 5, cc = idx & 31;
        Sld[rr][cc] = S[(aI + rr) * NN + aJ + cc];
    }
    for (int idx = lane; idx < 32 * 33; idx += 64)
        ((double*)Vtc)[idx] = 0.0;

    double aslice[16];
    #pragma unroll
    for (int u = 0; u < 16; ++u) {
        int kk = h * 16 + u;
        aslice[u] = (kk >= r) ? gload(&R[(aI + r) * NN + aI + kk]) : -1.0e30;
    }

    // ---- phaseA: deterministic middle-out k-tile order ----
    double P[16];
    #pragma unroll
    for (int x = 0; x < 16; ++x) P[x] = 0.0;
    const int nk = dd - 1;
    const int rg = lane >> 3, cg = lane & 7;
    const int r4 = rg * 4, c4 = cg * 4;
    int tl = (I + J) >> 1, tr = ((I + J) >> 1) + 1;
    for (int q = 0; q < nk; ++q) {
        int t;
        if ((q & 1) == 0) { if (tl >= I + 1) t = tl--; else t = tr++; }
        else              { if (tr <= J - 1) t = tr++; else t = tl--; }
        waitflag(flags, I, t);
        waitflag(flags, t, J);          // implies (t+1, J) done too
        int kt0 = t * BT;
        for (int w = 0; w < 16; ++w) {
            int idx = w * 64 + lane; int rr = idx >> 5, kk = idx & 31;
            Ast[kk][rr] = gload(&R[(aI + rr) * NN + kt0 + kk]);
            Bst[kk][rr] = gload(&C[(aJ + rr) * NN + kt0 + 1 + kk]);
        }
        for (int kk = 0; kk < 32; ++kk) {
            double2 av0 = *(const double2*)&Ast[kk][r4];
            double2 av1 = *(const double2*)&Ast[kk][r4 + 2];
            double2 bv0 = *(const double2*)&Bst[kk][c4];
            double2 bv1 = *(const double2*)&Bst[kk][c4 + 2];
            P[0]  = fmax(P[0],  av0.x + bv0.x); P[1]  = fmax(P[1],  av0.x + bv0.y);
            P[2]  = fmax(P[2],  av0.x + bv1.x); P[3]  = fmax(P[3],  av0.x + bv1.y);
            P[4]  = fmax(P[4],  av0.y + bv0.x); P[5]  = fmax(P[5],  av0.y + bv0.y);
            P[6]  = fmax(P[6],  av0.y + bv1.x); P[7]  = fmax(P[7],  av0.y + bv1.y);
            P[8]  = fmax(P[8],  av1.x + bv0.x); P[9]  = fmax(P[9],  av1.x + bv0.y);
            P[10] = fmax(P[10], av1.x + bv1.x); P[11] = fmax(P[11], av1.x + bv1.y);
            P[12] = fmax(P[12], av1.y + bv0.x); P[13] = fmax(P[13], av1.y + bv0.y);
            P[14] = fmax(P[14], av1.y + bv1.x); P[15] = fmax(P[15], av1.y + bv1.y);
        }
    }
    if (nk > 0) {
        #pragma unroll
        for (int x = 0; x < 4; ++x)
            #pragma unroll
            for (int y = 0; y < 4; ++y)
                Pld[r4 + x][c4 + y] = P[x * 4 + y];
    } else {
        for (int idx = lane; idx < 32 * 33; idx += 64)
            ((double*)Pld)[idx] = 0.0;
    }

    // ---- edges (flags covered: dd==1 by diag waits; dd>=2 by k-loop) ----
    if (lane < 33) edgeCol[lane] = gload(&R[(aI + lane) * NN + (aJ - 1)]);
    if (lane < 32) Vtc[lane][32] = gload(&R[(aI + 32) * NN + aJ + lane]);

    // ---- phaseB: 63 anti-diagonal micro-steps, barrier-free ----
    double vrow[16];
    #pragma unroll
    for (int u = 0; u < 16; ++u) vrow[u] = 0.0;

    for (int s = 0; s < 63; ++s) {
        int c = r + s - 31;
        bool act = ((unsigned)c < 32u);
        double acc = -1.0e30;
        if (act) {
            double t0 = -1.0e30, t1 = -1.0e30, t2 = -1.0e30, t3 = -1.0e30;
            #pragma unroll
            for (int u = 0; u < 16; u += 4) {
                int k0 = h * 16 + u;
                t0 = fmax(t0, aslice[u]     + Vtc[c][k0 + 1]);
                t1 = fmax(t1, aslice[u + 1] + Vtc[c][k0 + 2]);
                t2 = fmax(t2, aslice[u + 2] + Vtc[c][k0 + 3]);
                t3 = fmax(t3, aslice[u + 3] + Vtc[c][k0 + 4]);
            }
            double q0 = -1.0e30, q1 = -1.0e30, q2 = -1.0e30, q3 = -1.0e30;
            #pragma unroll
            for (int u = 0; u < 16; u += 4) {
                int m0 = h * 16 + u + 1;
                q0 = fmax(q0, vrow[u]     + DJJc[c][m0]);
                q1 = fmax(q1, vrow[u + 1] + DJJc[c][m0 + 1]);
                q2 = fmax(q2, vrow[u + 2] + DJJc[c][m0 + 2]);
                q3 = fmax(q3, vrow[u + 3] + DJJc[c][m0 + 3]);
            }
            acc = fmax(fmax(fmax(t0, t1), fmax(t2, t3)),
                       fmax(fmax(q0, q1), fmax(q2, q3)));
        }
        acc = fmax(acc, __shfl_xor(acc, 1));
        if (act) {
            double best = acc;
            best = fmax(best, edgeCol[r] + DJJc[c][0]);      // k = aJ-1
            best = fmax(best, Pld[r][c]);                    // external k-tiles
            double pv = (c > 0) ? Vtc[c - 1][r + 1] : edgeCol[r + 1];
            best = fmax(best, pv + (double)Sld[r][c]);       // pair
            if (h == 0) Vtc[c][r] = best;
            #pragma unroll
            for (int u = 0; u < 16; ++u)
                if (h * 16 + u == c) vrow[u] = best;
        }
    }

    for (int w = 0; w < 16; ++w) {
        int idx = w * 64 + lane; int rr = idx >> 5, cc = idx & 31;
        gstore(&R[(aI + rr) * NN + aJ + cc], Vtc[cc][rr]);
    }
    for (int w = 0; w < 16; ++w) {
        int idx = w * 64 + lane; int cc = idx >> 5, rr = idx & 31;
        gstore(&C[(aJ + cc) * NN + aI + rr], Vtc[cc][rr]);
    }
    if (lane == 0) setflag(flags, I, J);
}

// ---------------------------------------------------------------------------
// Traceback, software-pipelined: successor operands are loaded BEFORE the
// branch decision, hiding one L2 latency per event. Semantics unchanged.
// ---------------------------------------------------------------------------
__global__ __launch_bounds__(256) void traceback_kernel(const double* __restrict__ R,
                                                        const double* __restrict__ C,
                                                        const float* __restrict__ S,
                                                        float* __restrict__ out) {
    __shared__ int stk_i[2048];
    __shared__ int stk_j[2048];
    __shared__ double stk_v[2048];
    __shared__ int sh_top, sh_ii, sh_jj, sh_cmd;
    __shared__ double sred_v[4];
    __shared__ int sred_k[4];
    const double eps = 1e-9;
    if (threadIdx.x == 0) {
        sh_top = 1; stk_i[0] = 0; stk_j[0] = NN - 1; stk_v[0] = R[NN - 1];
    }
    __syncthreads();
    while (true) {
        if (threadIdx.x == 0) {
            int cmd = -1, top = sh_top;
            int i = 0, j = 0; double v = 0.0, a = 0.0, b2 = 0.0; float sv = 0.0f;
            bool have = false;
            while (true) {
                if (!have) {
                    if (top == 0) { cmd = -1; break; }
                    i = stk_i[--top]; j = stk_j[top]; v = stk_v[top];
                    if (j <= i || v <= eps) continue;
                    a  = R[(i + 1) * NN + j];
                    sv = S[i * NN + j];
                    b2 = R[(i + 1) * NN + j - 1];
                    have = true;
                    continue;
                }
                int ip = (i + 2 <= NN - 1) ? i + 2 : NN - 1;    // clamp (unused if OOB)
                int jl = (j - 2 >= 0) ? j - 2 : 0;
                double ar = R[ip * NN + j];
                double br = R[ip * NN + j - 1];
                double bl = R[ip * NN + jl];
                float  sr = S[(i + 1) * NN + j];
                float  sl = S[(i + 1) * NN + j - 1];
                if (a >= v - eps) {
                    ++i; v = a; a = ar; sv = sr; b2 = br;
                    if (j <= i || v <= eps) have = false;
                    continue;
                }
                if (sv > 0.0f && b2 + (double)sv >= v - eps) {
                    out[i * NN + j] = sv; out[j * NN + i] = sv;
                    ++i; --j; v = b2; a = br; sv = sl; b2 = bl;
                    if (j <= i || v <= eps) have = false;
                    continue;
                }
                sh_ii = i; sh_jj = j; cmd = 0; break;
            }
            sh_top = top; sh_cmd = cmd;
        }
        __syncthreads();
        if (sh_cmd < 0) break;
        int i = sh_ii, j = sh_jj;
        double bv = -1.0; int bk = 0x7fffffff;
        for (int k = i + threadIdx.x; k < j; k += 256) {
            double tv = R[i * NN + k] + C[j * NN + k + 1];
            if (tv > bv) { bv = tv; bk = k; }
        }
        for (int off = 32; off; off >>= 1) {
            double ov = __shfl_down(bv, off);
            int   ok = __shfl_down(bk, off);
            if (ov > bv || (ov == bv && ok < bk)) { bv = ov; bk = ok; }
        }
        if ((threadIdx.x & 63) == 0) { sred_v[threadIdx.x >> 6] = bv; sred_k[threadIdx.x >> 6] = bk; }
        __syncthreads();
        if (threadIdx.x == 0) {
            double fv = sred_v[0]; int fk = sred_k[0];
            for (int w = 1; w < 4; ++w)
                if (sred_v[w] > fv || (sred_v[w] == fv && sred_k[w] < fk)) { fv = sred_v[w]; fk = sred_k[w]; }
            int top = sh_top;
            stk_i[top] = sh_ii;  stk_j[top] = fk;    stk_v[top] = R[sh_ii * NN + fk];      ++top;
            stk_i[top] = fk + 1; stk_j[top] = sh_jj; stk_v[top] = C[sh_jj * NN + fk + 1];  ++top;
            sh_top = top;
        }
        __syncthreads();
    }
}

// ---------------------------------------------------------------------------
extern "C" void kernel_launch(void* const* d_in, const int* in_sizes, int n_in,
                              void* d_out, int out_size, void* d_ws, size_t ws_size,
                              hipStream_t stream) {
    const float* con  = (const float*)d_in[0];
    const float* feat = (const float*)d_in[1];
    float* out = (float*)d_out;

    char* ws = (char*)d_ws;
    double* R      = (double*)(ws);
    double* C      = (double*)(ws + (size_t)8  * 1024 * 1024);
    float*  S      = (float*) (ws + (size_t)16 * 1024 * 1024);
    int*    primes = (int*)   (ws + (size_t)20 * 1024 * 1024);
    int*    flags  = (int*)   (ws + (size_t)20 * 1024 * 1024 + 8192);

    primes_kernel<<<(NN + 255) / 256, 256, 0, stream>>>(feat, primes);
    prep_kernel<<<(NN * NN) / 256, 256, 0, stream>>>(con, primes, S, R, C, out, flags);
    nuss_tiles_kernel<<<NTILES, 64, 0, stream>>>(R, C, S, flags);
    traceback_kernel<<<1, 256, 0, stream>>>(R, C, S, out);
}

// Round 2
// 2070.543 us; speedup vs baseline: 1.1619x; 1.1619x over previous
//
#include <hip/hip_runtime.h>
#include <hip/hip_bf16.h>

#define NN 1024
#define BT 32
#define TT 32
#define NTILES ((TT * (TT + 1)) / 2)   // 528

// ---------------------------------------------------------------------------
// Fence-free cross-XCD protocol (validated round 1), now with BATCHED issue.
// All R/C traffic goes through the coherence point (MALL) via sc0 sc1 vector
// ops; no buffer_inv / buffer_wbl2 anywhere. Staging loads are issued as
// inline-asm global_load_dwordx2 back-to-back (one vmcnt(0) per block) --
// LLVM serializes monotonic atomic loads one-at-a-time (round-1 regression),
// asm restores single-latency batching.
//   setflag  = s_waitcnt vmcnt(0) + relaxed agent store (stores are sc0sc1)
//   waitflag = relaxed agent poll + compiler barrier
// Transitivity ("flag(t,J) => flag(t+1,J) data visible") holds because MALL
// is the single serialization point: producers drain vmcnt before flagging,
// and no L1/L2 ever caches R/C during this kernel.
// ---------------------------------------------------------------------------
__device__ __forceinline__ double gload_cc(const double* p) {
    double v;
    asm volatile("global_load_dwordx2 %0, %1, off sc0 sc1" : "=v"(v) : "v"(p));
    return v;
}
__device__ __forceinline__ void vwait() {
    asm volatile("s_waitcnt vmcnt(0)" ::: "memory");
}
__device__ __forceinline__ void gstore(double* p, double v) {
    __hip_atomic_store(p, v, __ATOMIC_RELAXED, __HIP_MEMORY_SCOPE_AGENT);
}

__device__ __forceinline__ void waitflag(const int* f, int a, int b) {
    const int* p = &f[(a * TT + b) << 4];
    while (!__hip_atomic_load(p, __ATOMIC_RELAXED, __HIP_MEMORY_SCOPE_AGENT))
        __builtin_amdgcn_s_sleep(1);
    asm volatile("" ::: "memory");
}
// Dual poll: both flag loads in flight together (saves one MALL round-trip).
__device__ __forceinline__ void waitflag2(const int* f, int a0, int b0, int a1, int b1) {
    const int* p0 = &f[(a0 * TT + b0) << 4];
    const int* p1 = &f[(a1 * TT + b1) << 4];
    while (true) {
        int v0 = __hip_atomic_load(p0, __ATOMIC_RELAXED, __HIP_MEMORY_SCOPE_AGENT);
        int v1 = __hip_atomic_load(p1, __ATOMIC_RELAXED, __HIP_MEMORY_SCOPE_AGENT);
        if (v0 & v1) break;
        __builtin_amdgcn_s_sleep(1);
    }
    asm volatile("" ::: "memory");
}
__device__ __forceinline__ void setflag(int* f, int a, int b) {
    asm volatile("s_waitcnt vmcnt(0)" ::: "memory");  // data at coherence point
    __hip_atomic_store(&f[(a * TT + b) << 4], 1, __ATOMIC_RELAXED, __HIP_MEMORY_SCOPE_AGENT);
}

// ---------------------------------------------------------------------------
__global__ void primes_kernel(const float* __restrict__ feat, int* __restrict__ primes) {
    int i = blockIdx.x * blockDim.x + threadIdx.x;
    if (i < NN) {
        float best = feat[i * NN];
        int arg = 0;
        for (int ch = 1; ch < 4; ++ch) {
            float v = feat[ch * NN * NN + i * NN];
            if (v > best) { best = v; arg = ch; }
        }
        const int P[4] = {2, 3, 5, 7};
        primes[i] = P[arg];
    }
}

__global__ void prep_kernel(const float* __restrict__ con, const int* __restrict__ primes,
                            float* __restrict__ S, double* __restrict__ R,
                            double* __restrict__ C, float* __restrict__ out,
                            int* __restrict__ flags) {
    int idx = blockIdx.x * blockDim.x + threadIdx.x;
    int i = idx >> 10;
    int j = idx & (NN - 1);
    float c = (con[idx] + con[j * NN + i]) * 0.5f;
    int prod = primes[i] * primes[j];
    bool canon = (prod == 14) | (prod == 15) | (prod == 35);
    int d = i - j; if (d < 0) d = -d;
    S[idx] = (canon && d >= 4) ? c : 0.0f;
    R[idx] = 0.0;
    C[idx] = 0.0;
    out[idx] = 0.0f;
    if (idx < TT * TT * 16) flags[idx] = 0;
}

// ---------------------------------------------------------------------------
// Dataflow DP, one wave per 32x32 tile. Exactness: every candidate is one
// fp64 add of stored values; extra candidates are dominated (-1e30+x<0<=dp,
// stale-0 + 0 = 0 <= dp). fmax order-insensitive => DP bitwise == numpy.
// ---------------------------------------------------------------------------
__global__ __launch_bounds__(64) void nuss_tiles_kernel(double* __restrict__ R,
                                                        double* __restrict__ C,
                                                        const float* __restrict__ S,
                                                        int* __restrict__ flags) {
    __shared__ double DJJc[32][33];                         // DJJc[c][m]=V(aJ+m,aJ+c); [32]=0
    __shared__ double Vtc[32][33];                          // Vtc[c][r]=V(aI+r,aJ+c); [32]=edge
    __shared__ __attribute__((aligned(16))) double Ast[32][34]; // Ast[kk][r]=V(aI+r,kt0+kk)
    __shared__ __attribute__((aligned(16))) double Bst[32][34]; // Bst[kk][c]=V(kt0+kk+1,aJ+c)
    __shared__ double Pld[32][33];
    __shared__ float  Sld[32][32];
    __shared__ double edgeCol[33];                          // V(aI+rr, aJ-1)

    int b = blockIdx.x, dd = 0;
    while (b >= TT - dd) { b -= TT - dd; ++dd; }
    const int I = b, J = b + dd;
    const int aI = I * BT, aJ = J * BT;
    const int lane = threadIdx.x;
    const int r = lane >> 1;
    const int h = lane & 1;

    if (dd == 0) {
        // ---------------- diagonal tile ----------------
        for (int w = 0; w < 16; ++w) {
            int idx = w * 64 + lane; int rr = idx >> 5, cc = idx & 31;
            Sld[rr][cc] = S[(aI + rr) * NN + aI + cc];
        }
        for (int idx = lane; idx < 32 * 33; idx += 64)
            ((double*)Vtc)[idx] = 0.0;
        double vrow[16];
        #pragma unroll
        for (int u = 0; u < 16; ++u) vrow[u] = 0.0;

        for (int s = 1; s <= 31; ++s) {
            int c = r + s;
            bool act = (c <= 31);
            double acc = 0.0;
            if (act) {
                double t0 = 0.0, t1 = 0.0, t2 = 0.0, t3 = 0.0;
                #pragma unroll
                for (int u = 0; u < 16; u += 4) {
                    int k0 = h * 16 + u;
                    t0 = fmax(t0, vrow[u]     + Vtc[c][k0 + 1]);
                    t1 = fmax(t1, vrow[u + 1] + Vtc[c][k0 + 2]);
                    t2 = fmax(t2, vrow[u + 2] + Vtc[c][k0 + 3]);
                    t3 = fmax(t3, vrow[u + 3] + Vtc[c][k0 + 4]);
                }
                acc = fmax(fmax(t0, t1), fmax(t2, t3));
            }
            acc = fmax(acc, __shfl_xor(acc, 1));
            if (act) {
                double best = fmax(acc, Vtc[c - 1][r + 1] + (double)Sld[r][c]);
                if (h == 0) Vtc[c][r] = best;
                #pragma unroll
                for (int u = 0; u < 16; ++u)
                    if (h * 16 + u == c) vrow[u] = best;
            }
        }
        for (int w = 0; w < 16; ++w) {
            int idx = w * 64 + lane; int rr = idx >> 5, cc = idx & 31;
            gstore(&R[(aI + rr) * NN + aI + cc], Vtc[cc][rr]);
        }
        for (int w = 0; w < 16; ++w) {
            int idx = w * 64 + lane; int cc = idx >> 5, rr = idx & 31;
            gstore(&C[(aI + cc) * NN + aI + rr], Vtc[cc][rr]);
        }
        if (lane == 0) setflag(flags, I, I);
        return;
    }

    // ---------------- off-diagonal tile ----------------
    waitflag2(flags, I, I, J, J);

    // Batched MALL loads: DJJc (16/lane) + aslice (16/lane), issued together;
    // Sld/Vtc-zero overlap the flight time; single vmcnt(0).
    double rd[16], ras[16];
    #pragma unroll
    for (int w = 0; w < 16; ++w) {
        int idx = w * 64 + lane; int cc = idx >> 5, mm = idx & 31;
        rd[w] = gload_cc(&C[(aJ + cc) * NN + aJ + mm]);
    }
    #pragma unroll
    for (int u = 0; u < 16; ++u) {
        int kk = h * 16 + u;
        ras[u] = gload_cc(&R[(aI + r) * NN + aI + kk]);
    }
    for (int w = 0; w < 16; ++w) {
        int idx = w * 64 + lane; int rr = idx >> 5, cc = idx & 31;
        Sld[rr][cc] = S[(aI + rr) * NN + aJ + cc];
    }
    for (int idx = lane; idx < 32 * 33; idx += 64)
        ((double*)Vtc)[idx] = 0.0;
    vwait();
    #pragma unroll
    for (int w = 0; w < 16; ++w) {
        int idx = w * 64 + lane; int cc = idx >> 5, mm = idx & 31;
        DJJc[cc][mm] = rd[w];
    }
    if (lane < 32) DJJc[lane][32] = 0.0;

    double aslice[16];
    #pragma unroll
    for (int u = 0; u < 16; ++u) {
        int kk = h * 16 + u;
        aslice[u] = (kk >= r) ? ras[u] : -1.0e30;
    }

    // ---- phaseA: deterministic middle-out k-tile order ----
    double P[16];
    #pragma unroll
    for (int x = 0; x < 16; ++x) P[x] = 0.0;
    const int nk = dd - 1;
    const int rg = lane >> 3, cg = lane & 7;
    const int r4 = rg * 4, c4 = cg * 4;
    int tl = (I + J) >> 1, tr = ((I + J) >> 1) + 1;
    for (int q = 0; q < nk; ++q) {
        int t;
        if ((q & 1) == 0) { if (tl >= I + 1) t = tl--; else t = tr++; }
        else              { if (tr <= J - 1) t = tr++; else t = tl--; }
        waitflag2(flags, I, t, t, J);   // (t,J) implies (t+1,J) done too
        int kt0 = t * BT;
        double ra[16], rb[16];
        #pragma unroll
        for (int w = 0; w < 16; ++w) {
            int idx = w * 64 + lane; int rr = idx >> 5, kk = idx & 31;
            ra[w] = gload_cc(&R[(aI + rr) * NN + kt0 + kk]);
            rb[w] = gload_cc(&C[(aJ + rr) * NN + kt0 + 1 + kk]);
        }
        vwait();
        #pragma unroll
        for (int w = 0; w < 16; ++w) {
            int idx = w * 64 + lane; int rr = idx >> 5, kk = idx & 31;
            Ast[kk][rr] = ra[w];
            Bst[kk][rr] = rb[w];
        }
        for (int kk = 0; kk < 32; ++kk) {
            double2 av0 = *(const double2*)&Ast[kk][r4];
            double2 av1 = *(const double2*)&Ast[kk][r4 + 2];
            double2 bv0 = *(const double2*)&Bst[kk][c4];
            double2 bv1 = *(const double2*)&Bst[kk][c4 + 2];
            P[0]  = fmax(P[0],  av0.x + bv0.x); P[1]  = fmax(P[1],  av0.x + bv0.y);
            P[2]  = fmax(P[2],  av0.x + bv1.x); P[3]  = fmax(P[3],  av0.x + bv1.y);
            P[4]  = fmax(P[4],  av0.y + bv0.x); P[5]  = fmax(P[5],  av0.y + bv0.y);
            P[6]  = fmax(P[6],  av0.y + bv1.x); P[7]  = fmax(P[7],  av0.y + bv1.y);
            P[8]  = fmax(P[8],  av1.x + bv0.x); P[9]  = fmax(P[9],  av1.x + bv0.y);
            P[10] = fmax(P[10], av1.x + bv1.x); P[11] = fmax(P[11], av1.x + bv1.y);
            P[12] = fmax(P[12], av1.y + bv0.x); P[13] = fmax(P[13], av1.y + bv0.y);
            P[14] = fmax(P[14], av1.y + bv1.x); P[15] = fmax(P[15], av1.y + bv1.y);
        }
    }
    if (nk > 0) {
        #pragma unroll
        for (int x = 0; x < 4; ++x)
            #pragma unroll
            for (int y = 0; y < 4; ++y)
                Pld[r4 + x][c4 + y] = P[x * 4 + y];
    } else {
        for (int idx = lane; idx < 32 * 33; idx += 64)
            ((double*)Pld)[idx] = 0.0;
    }

    // ---- edges (flags covered: dd==1 by diag waits; dd>=2 by k-loop) ----
    double ec = 0.0, ve = 0.0;
    if (lane < 33) ec = gload_cc(&R[(aI + lane) * NN + (aJ - 1)]);
    if (lane < 32) ve = gload_cc(&R[(aI + 32) * NN + aJ + lane]);
    vwait();
    if (lane < 33) edgeCol[lane] = ec;
    if (lane < 32) Vtc[lane][32] = ve;

    // ---- phaseB: 63 anti-diagonal micro-steps, barrier-free ----
    double vrow[16];
    #pragma unroll
    for (int u = 0; u < 16; ++u) vrow[u] = 0.0;

    for (int s = 0; s < 63; ++s) {
        int c = r + s - 31;
        bool act = ((unsigned)c < 32u);
        double acc = -1.0e30;
        if (act) {
            double t0 = -1.0e30, t1 = -1.0e30, t2 = -1.0e30, t3 = -1.0e30;
            #pragma unroll
            for (int u = 0; u < 16; u += 4) {
                int k0 = h * 16 + u;
                t0 = fmax(t0, aslice[u]     + Vtc[c][k0 + 1]);
                t1 = fmax(t1, aslice[u + 1] + Vtc[c][k0 + 2]);
                t2 = fmax(t2, aslice[u + 2] + Vtc[c][k0 + 3]);
                t3 = fmax(t3, aslice[u + 3] + Vtc[c][k0 + 4]);
            }
            double q0 = -1.0e30, q1 = -1.0e30, q2 = -1.0e30, q3 = -1.0e30;
            #pragma unroll
            for (int u = 0; u < 16; u += 4) {
                int m0 = h * 16 + u + 1;
                q0 = fmax(q0, vrow[u]     + DJJc[c][m0]);
                q1 = fmax(q1, vrow[u + 1] + DJJc[c][m0 + 1]);
                q2 = fmax(q2, vrow[u + 2] + DJJc[c][m0 + 2]);
                q3 = fmax(q3, vrow[u + 3] + DJJc[c][m0 + 3]);
            }
            acc = fmax(fmax(fmax(t0, t1), fmax(t2, t3)),
                       fmax(fmax(q0, q1), fmax(q2, q3)));
        }
        acc = fmax(acc, __shfl_xor(acc, 1));
        if (act) {
            double best = acc;
            best = fmax(best, edgeCol[r] + DJJc[c][0]);      // k = aJ-1
            best = fmax(best, Pld[r][c]);                    // external k-tiles
            double pv = (c > 0) ? Vtc[c - 1][r + 1] : edgeCol[r + 1];
            best = fmax(best, pv + (double)Sld[r][c]);       // pair
            if (h == 0) Vtc[c][r] = best;
            #pragma unroll
            for (int u = 0; u < 16; ++u)
                if (h * 16 + u == c) vrow[u] = best;
        }
    }

    for (int w = 0; w < 16; ++w) {
        int idx = w * 64 + lane; int rr = idx >> 5, cc = idx & 31;
        gstore(&R[(aI + rr) * NN + aJ + cc], Vtc[cc][rr]);
    }
    for (int w = 0; w < 16; ++w) {
        int idx = w * 64 + lane; int cc = idx >> 5, rr = idx & 31;
        gstore(&C[(aJ + cc) * NN + aI + rr], Vtc[cc][rr]);
    }
    if (lane == 0) setflag(flags, I, J);
}

// ---------------------------------------------------------------------------
// Traceback, software-pipelined: successor operands are loaded BEFORE the
// branch decision, hiding one L2 latency per event. Semantics unchanged.
// ---------------------------------------------------------------------------
__global__ __launch_bounds__(256) void traceback_kernel(const double* __restrict__ R,
                                                        const double* __restrict__ C,
                                                        const float* __restrict__ S,
                                                        float* __restrict__ out) {
    __shared__ int stk_i[2048];
    __shared__ int stk_j[2048];
    __shared__ double stk_v[2048];
    __shared__ int sh_top, sh_ii, sh_jj, sh_cmd;
    __shared__ double sred_v[4];
    __shared__ int sred_k[4];
    const double eps = 1e-9;
    if (threadIdx.x == 0) {
        sh_top = 1; stk_i[0] = 0; stk_j[0] = NN - 1; stk_v[0] = R[NN - 1];
    }
    __syncthreads();
    while (true) {
        if (threadIdx.x == 0) {
            int cmd = -1, top = sh_top;
            int i = 0, j = 0; double v = 0.0, a = 0.0, b2 = 0.0; float sv = 0.0f;
            bool have = false;
            while (true) {
                if (!have) {
                    if (top == 0) { cmd = -1; break; }
                    i = stk_i[--top]; j = stk_j[top]; v = stk_v[top];
                    if (j <= i || v <= eps) continue;
                    a  = R[(i + 1) * NN + j];
                    sv = S[i * NN + j];
                    b2 = R[(i + 1) * NN + j - 1];
                    have = true;
                    continue;
                }
                int ip = (i + 2 <= NN - 1) ? i + 2 : NN - 1;    // clamp (unused if OOB)
                int jl = (j - 2 >= 0) ? j - 2 : 0;
                double ar = R[ip * NN + j];
                double br = R[ip * NN + j - 1];
                double bl = R[ip * NN + jl];
                float  sr = S[(i + 1) * NN + j];
                float  sl = S[(i + 1) * NN + j - 1];
                if (a >= v - eps) {
                    ++i; v = a; a = ar; sv = sr; b2 = br;
                    if (j <= i || v <= eps) have = false;
                    continue;
                }
                if (sv > 0.0f && b2 + (double)sv >= v - eps) {
                    out[i * NN + j] = sv; out[j * NN + i] = sv;
                    ++i; --j; v = b2; a = br; sv = sl; b2 = bl;
                    if (j <= i || v <= eps) have = false;
                    continue;
                }
                sh_ii = i; sh_jj = j; cmd = 0; break;
            }
            sh_top = top; sh_cmd = cmd;
        }
        __syncthreads();
        if (sh_cmd < 0) break;
        int i = sh_ii, j = sh_jj;
        double bv = -1.0; int bk = 0x7fffffff;
        for (int k = i + threadIdx.x; k < j; k += 256) {
            double tv = R[i * NN + k] + C[j * NN + k + 1];
            if (tv > bv) { bv = tv; bk = k; }
        }
        for (int off = 32; off; off >>= 1) {
            double ov = __shfl_down(bv, off);
            int   ok = __shfl_down(bk, off);
            if (ov > bv || (ov == bv && ok < bk)) { bv = ov; bk = ok; }
        }
        if ((threadIdx.x & 63) == 0) { sred_v[threadIdx.x >> 6] = bv; sred_k[threadIdx.x >> 6] = bk; }
        __syncthreads();
        if (threadIdx.x == 0) {
            double fv = sred_v[0]; int fk = sred_k[0];
            for (int w = 1; w < 4; ++w)
                if (sred_v[w] > fv || (sred_v[w] == fv && sred_k[w] < fk)) { fv = sred_v[w]; fk = sred_k[w]; }
            int top = sh_top;
            stk_i[top] = sh_ii;  stk_j[top] = fk;    stk_v[top] = R[sh_ii * NN + fk];      ++top;
            stk_i[top] = fk + 1; stk_j[top] = sh_jj; stk_v[top] = C[sh_jj * NN + fk + 1];  ++top;
            sh_top = top;
        }
        __syncthreads();
    }
}

// ---------------------------------------------------------------------------
extern "C" void kernel_launch(void* const* d_in, const int* in_sizes, int n_in,
                              void* d_out, int out_size, void* d_ws, size_t ws_size,
                              hipStream_t stream) {
    const float* con  = (const float*)d_in[0];
    const float* feat = (const float*)d_in[1];
    float* out = (float*)d_out;

    char* ws = (char*)d_ws;
    double* R      = (double*)(ws);
    double* C      = (double*)(ws + (size_t)8  * 1024 * 1024);
    float*  S      = (float*) (ws + (size_t)16 * 1024 * 1024);
    int*    primes = (int*)   (ws + (size_t)20 * 1024 * 1024);
    int*    flags  = (int*)   (ws + (size_t)20 * 1024 * 1024 + 8192);

    primes_kernel<<<(NN + 255) / 256, 256, 0, stream>>>(feat, primes);
    prep_kernel<<<(NN * NN) / 256, 256, 0, stream>>>(con, primes, S, R, C, out, flags);
    nuss_tiles_kernel<<<NTILES, 64, 0, stream>>>(R, C, S, flags);
    traceback_kernel<<<1, 256, 0, stream>>>(R, C, S, out);
}